// Round 5
// baseline (204.094 us; speedup 1.0000x reference)
//
#include <hip/hip_runtime.h>

typedef __bf16 bf16x8 __attribute__((ext_vector_type(8)));
typedef __bf16 bf16x4 __attribute__((ext_vector_type(4)));
typedef short s16x4 __attribute__((ext_vector_type(4)));
typedef float f32x4 __attribute__((ext_vector_type(4)));
typedef unsigned short u16x8 __attribute__((ext_vector_type(8)));
typedef unsigned short u16x4 __attribute__((ext_vector_type(4)));
typedef unsigned int u32x2 __attribute__((ext_vector_type(2)));
typedef unsigned int __attribute__((address_space(1))) as1_uint;
typedef unsigned int __attribute__((address_space(3))) as3_uint;

#define S_LEN 2048
#define NB 4
#define NH 16
#define HD 64
#define DM 1024

// 0.125 (1/sqrt(64)) * log2(e): Q is pre-scaled so attn does exp2 directly.
#define Q_SCALE 0.18033688011112042f

__device__ __forceinline__ unsigned short f2bf(float f) {
  union { float f; unsigned int u; } v; v.f = f;
  unsigned int r = v.u + 0x7fffu + ((v.u >> 16) & 1u);
  return (unsigned short)(r >> 16);
}

__device__ __forceinline__ unsigned int fbits(float f) {
  union { float f; unsigned int u; } v; v.f = f;
  return v.u;
}

// 16x16x16 bf16 MFMA with builtin-name portability.
__device__ __forceinline__ f32x4 mfma16(u16x4 a, u16x4 b, f32x4 c) {
#if __has_builtin(__builtin_amdgcn_mfma_f32_16x16x16_bf16)
  return __builtin_amdgcn_mfma_f32_16x16x16_bf16(
      __builtin_bit_cast(bf16x4, a), __builtin_bit_cast(bf16x4, b), c, 0, 0, 0);
#else
  return __builtin_amdgcn_mfma_f32_16x16x16bf16_1k(
      __builtin_bit_cast(s16x4, a), __builtin_bit_cast(s16x4, b), c, 0, 0, 0);
#endif
}

// ---------- kernel 1: fused conversions ----------
// blocks [0,4096): X fp32 -> bf16 (layout preserved, 8192x1024)
// blocks [4096,7168): W (K,N) fp32 -> WT (N,K) bf16 for q/k/v
__global__ __launch_bounds__(256) void cvt_all(const float* __restrict__ x,
                                               unsigned short* __restrict__ xb,
                                               const float* __restrict__ Wq,
                                               const float* __restrict__ Wk,
                                               const float* __restrict__ Wv,
                                               unsigned short* __restrict__ wt) {
  __shared__ float tile[32][33];
  const int bid = blockIdx.x;
  if (bid < 4096) {
    int i = (bid * 256 + threadIdx.x) * 8;
    f32x4 a = *(const f32x4*)(x + i);
    f32x4 b = *(const f32x4*)(x + i + 4);
    u16x8 o;
    o[0] = f2bf(a[0]); o[1] = f2bf(a[1]); o[2] = f2bf(a[2]); o[3] = f2bf(a[3]);
    o[4] = f2bf(b[0]); o[5] = f2bf(b[1]); o[6] = f2bf(b[2]); o[7] = f2bf(b[3]);
    *(u16x8*)(xb + i) = o;
  } else {
    const int r = bid - 4096;
    const int z = r >> 10;
    const int rr = r & 1023;
    const float* W = (z == 0) ? Wq : (z == 1) ? Wk : Wv;
    unsigned short* WT = wt + (size_t)z * DM * DM;
    int tx = threadIdx.x & 31, ty = threadIdx.x >> 5;
    int k0 = (rr & 31) * 32, n0 = (rr >> 5) * 32;
#pragma unroll
    for (int i = 0; i < 4; ++i)
      tile[ty + 8 * i][tx] = W[(size_t)(k0 + ty + 8 * i) * DM + n0 + tx];
    __syncthreads();
#pragma unroll
    for (int i = 0; i < 4; ++i)
      WT[(size_t)(n0 + ty + 8 * i) * DM + k0 + tx] = f2bf(tile[tx][ty + 8 * i]);
  }
}

// ---------- kernel 2: QKV GEMM: Y = Xb @ W + b ----------
// 256x128 tile, BK=64, 8 waves (4M x 2N, 64x64 each), TRIPLE-buffered LDS with
// prefetch distance 2 and counted vmcnt (never 0 in steady state):
//   iter t: stage(t+2) -> buf[(t+2)%3]   (that buffer's reads ended at t-1)
//           ds_read + 32 MFMA on buf[t%3]
//           s_waitcnt vmcnt(6)           (stage(t+1) landed; t+2 in flight)
//           s_barrier                    (publish buf[(t+1)%3])
// One raw barrier per K-tile, no vmcnt(0) drain in the main loop. LDS chunk
// XOR swizzle (c^row&7) folded into the GLOBAL source address.
// z=0 -> Q*Q_SCALE (B,H,S,HD) bf16 ; z=1 -> K (B,H,S,HD) bf16
// z=2 -> V^T (B,H,64,S) bf16 with an 8B-unit swizzle baked into the global
//        layout: within each 64-seq window, unit' = unit ^ (d&15). This makes
//        attn's V b64 LDS reads provably bank-conflict-free (each 16-lane
//        quad-phase touches all 32 banks exactly once) while keeping attn's
//        V staging LINEAR (gload_lds-compatible).
#define QKV_LDS_BYTES 147456  // 3 * (256*64 + 128*64) * 2
__global__ __launch_bounds__(512, 2) void qkv_gemm(const unsigned short* __restrict__ xb,
                                                   const unsigned short* __restrict__ wt,
                                                   const float* __restrict__ bq,
                                                   const float* __restrict__ bk,
                                                   const float* __restrict__ bv,
                                                   unsigned short* __restrict__ qo,
                                                   unsigned short* __restrict__ ko,
                                                   unsigned short* __restrict__ vto) {
  extern __shared__ char smem_dyn[];
  unsigned short* As = (unsigned short*)smem_dyn;             // 3 x 256x64
  unsigned short* Bs = As + 3 * 256 * 64;                     // 3 x 128x64
  const int z = blockIdx.z;
  const unsigned short* WT = wt + (size_t)z * DM * DM;
  const float* bias = (z == 0) ? bq : (z == 1) ? bk : bv;
  const int m0 = blockIdx.x * 256;
  const int n0 = blockIdx.y * 128;
  const int tid = threadIdx.x;
  const int wave = tid >> 6, lane = tid & 63, quad = lane >> 4, lw = lane & 15;
  const int wm = (wave >> 1) * 64, wn = (wave & 1) * 64;

  f32x4 acc[4][4];
#pragma unroll
  for (int mt = 0; mt < 4; ++mt)
#pragma unroll
    for (int nt = 0; nt < 4; ++nt) acc[mt][nt] = (f32x4){0.f, 0.f, 0.f, 0.f};

  // ---- staging: 6 global_load_lds (16B) per thread per K-tile ----
  auto stage = [&](int tile) {
    const int kt = tile * 64;
    const int bsel = tile % 3;
    unsigned short* Ad = As + bsel * (256 * 64);
    unsigned short* Bd = Bs + bsel * (128 * 64);
#pragma unroll
    for (int i = 0; i < 4; ++i) {
      int c = i * 512 + tid;
      int row = c >> 3, scn = (c & 7) ^ (row & 7);
      __builtin_amdgcn_global_load_lds((const as1_uint*)(xb + (size_t)(m0 + row) * DM + kt + scn * 8),
                                       (as3_uint*)(Ad + c * 8), 16, 0, 0);
    }
#pragma unroll
    for (int i = 0; i < 2; ++i) {
      int c = i * 512 + tid;
      int row = c >> 3, scn = (c & 7) ^ (row & 7);
      __builtin_amdgcn_global_load_lds((const as1_uint*)(WT + (size_t)(n0 + row) * DM + kt + scn * 8),
                                       (as3_uint*)(Bd + c * 8), 16, 0, 0);
    }
  };

  // prologue: tiles 0 and 1 in flight; wait for tile 0 (6 loads still out)
  stage(0);
  stage(1);
  asm volatile("s_waitcnt vmcnt(6)" ::: "memory");
  __builtin_amdgcn_s_barrier();
  asm volatile("" ::: "memory");

#pragma unroll
  for (int t = 0; t < 16; ++t) {
    if (t + 2 < 16) stage(t + 2);

    const unsigned short* Ab = As + (t % 3) * (256 * 64);
    const unsigned short* Bb = Bs + (t % 3) * (128 * 64);
    bf16x8 af[2][4], bfq[2][4];
#pragma unroll
    for (int k = 0; k < 2; ++k) {
#pragma unroll
      for (int mt = 0; mt < 4; ++mt) {
        int r = wm + mt * 16 + lw;
        af[k][mt] = *(const bf16x8*)(Ab + r * 64 + (((k * 4 + quad) ^ (r & 7)) * 8));
      }
#pragma unroll
      for (int nt = 0; nt < 4; ++nt) {
        int r = wn + nt * 16 + lw;
        bfq[k][nt] = *(const bf16x8*)(Bb + r * 64 + (((k * 4 + quad) ^ (r & 7)) * 8));
      }
    }
#pragma unroll
    for (int k = 0; k < 2; ++k)
#pragma unroll
      for (int mt = 0; mt < 4; ++mt)
#pragma unroll
        for (int nt = 0; nt < 4; ++nt)
          acc[mt][nt] = __builtin_amdgcn_mfma_f32_16x16x32_bf16(af[k][mt], bfq[k][nt], acc[mt][nt], 0, 0, 0);

    if (t < 15) {
      if (t < 14) asm volatile("s_waitcnt vmcnt(6)" ::: "memory");
      else        asm volatile("s_waitcnt vmcnt(0)" ::: "memory");
      __builtin_amdgcn_s_barrier();
      asm volatile("" ::: "memory");
    }
  }

  float bias4[4];
#pragma unroll
  for (int nt = 0; nt < 4; ++nt) bias4[nt] = bias[n0 + wn + nt * 16 + lw];

  if (z < 2) {
    unsigned short* dst = (z == 0) ? qo : ko;
    const float sc = (z == 0) ? Q_SCALE : 1.0f;
#pragma unroll
    for (int mt = 0; mt < 4; ++mt) {
#pragma unroll
      for (int nt = 0; nt < 4; ++nt) {
        int n = n0 + wn + nt * 16 + lw;
        int h = n >> 6, d = n & 63;
#pragma unroll
        for (int r = 0; r < 4; ++r) {
          int m = m0 + wm + mt * 16 + quad * 4 + r;
          int b = m >> 11, s = m & 2047;
          dst[((size_t)(b * NH + h) * S_LEN + s) * HD + d] = f2bf((acc[mt][nt][r] + bias4[nt]) * sc);
        }
      }
    }
  } else {
#pragma unroll
    for (int mt = 0; mt < 4; ++mt) {
#pragma unroll
      for (int nt = 0; nt < 4; ++nt) {
        int n = n0 + wn + nt * 16 + lw;
        int h = n >> 6, d = n & 63;
        int mb = m0 + wm + mt * 16 + quad * 4;
        int b = mb >> 11, s = mb & 2047;
        u16x4 pk;
#pragma unroll
        for (int r = 0; r < 4; ++r) pk[r] = f2bf(acc[mt][nt][r] + bias4[nt]);
        // 8B-unit swizzle within each 64-seq window: unit' = unit ^ (d&15)
        int u = s >> 2;
        int us = ((u & ~15) | ((u & 15) ^ (d & 15))) << 2;
        *(u16x4*)(vto + ((size_t)(b * NH + h) * HD + d) * S_LEN + us) = pk;
      }
    }
  }
}

// ---------- kernel 3: causal flash attention, register-resident P ------------
// One 64-q-row strip per block (2048 blocks), strip qidx processes tiles
// 0..qidx. Longest strips dispatched first (LPT) + dynamic refill. K AND V
// double-buffered in LDS (32 KB -> 5 blocks/CU, 20 waves).
// Bank-conflict fixes (round-4 counter: 8.65M conflict cycles):
//  - K chunk swizzle now includes row bit 3: c ^ (r&7) ^ (((r>>3)&1)<<2),
//    so lanes lw and lw+8 (same quad) no longer alias the same 4 banks.
//  - V carries an 8B-unit swizzle baked into its GLOBAL layout by qkv
//    (unit' = unit ^ (d&15) per 64-seq window): staging is linear, and the
//    b64 fragment read at p8 = (4g+quad)^lw touches all 32 banks exactly
//    once per 16-lane quad-phase. Conflict-free by construction.
// S^T = K*Q^T via mfma 16x16x32 (A=K, B=Q); S^T's C-layout IS the A-layout of
// mfma 16x16x16 so P feeds PV from registers. l = P@1. Prefetch for tile t+1
// issued AFTER the barrier publishing tile t.
__global__ __launch_bounds__(256, 5) void attn(const unsigned short* __restrict__ Qb,
                                               const unsigned short* __restrict__ Kb,
                                               const unsigned short* __restrict__ Vtb,
                                               float* __restrict__ out) {
  const int flat = blockIdx.x;
  const int bh_lo = flat & 7;          // XCD affinity: strips of a bh group share XCD
  const int rest = flat >> 3;
  const int qidx = 31 - (rest >> 3);   // descending strip length: LPT scheduling
  const int bh_hi = rest & 7;
  const int bh = bh_lo | (bh_hi << 3);
  const int b = bh >> 4, h = bh & 15;
  const int tid = threadIdx.x;
  const int wave = tid >> 6, lane = tid & 63;
  const int quad = lane >> 4, lw = lane & 15;
  const unsigned short* Qp = Qb + (size_t)bh * S_LEN * HD;
  const unsigned short* Kp = Kb + (size_t)bh * S_LEN * HD;
  const unsigned short* Vp = Vtb + (size_t)bh * HD * S_LEN;

  __shared__ __align__(16) unsigned short Kl[2][64 * 64];
  __shared__ __align__(16) unsigned short Vl[2][64 * 64];

  // Q fragments (B-operand: n=qrow=lane&15, k=quad*8+j)
  const int qbase = qidx * 64;
  bf16x8 aq[2];
#pragma unroll
  for (int kc = 0; kc < 2; ++kc)
    aq[kc] = *(const bf16x8*)(Qp + (size_t)(qbase + wave * 16 + lw) * HD + kc * 32 + quad * 8);

  u16x4 ones4;
#pragma unroll
  for (int i = 0; i < 4; ++i) ones4[i] = 0x3F80;

  f32x4 accO[4];
  f32x4 accL = (f32x4){0.f, 0.f, 0.f, 0.f};
#pragma unroll
  for (int dg = 0; dg < 4; ++dg) accO[dg] = (f32x4){0.f, 0.f, 0.f, 0.f};

  const int qr = qbase + wave * 16 + lw;
  const int T = qidx + 1;
  const int swk = (lw & 7) ^ (((lw >> 3) & 1) << 2);  // K-read chunk swizzle

  // prologue: stage K+V tile 0 into buffer 0 (4 x 16B gload_lds per thread)
#pragma unroll
  for (int i = 0; i < 2; ++i) {
    int idx = i * 256 + tid;
    int r = idx >> 3;
    int ck = (idx & 7) ^ (r & 7) ^ (((r >> 3) & 1) << 2);
    __builtin_amdgcn_global_load_lds((const as1_uint*)(Kp + (size_t)r * HD + ck * 8),
                                     (as3_uint*)(Kl[0] + idx * 8), 16, 0, 0);
    __builtin_amdgcn_global_load_lds((const as1_uint*)(Vp + (size_t)r * S_LEN + (idx & 7) * 8),
                                     (as3_uint*)(Vl[0] + idx * 8), 16, 0, 0);
  }

  for (int t = 0; t < T; ++t) {
    const int kv = t * 64;
    const int cur = t & 1;
    __syncthreads();  // buf[cur] staged; all waves done reading buf[cur^1]

    if (t + 1 < T) {  // prefetch next tile; drains only at NEXT barrier
      const int kvn = kv + 64;
#pragma unroll
      for (int i = 0; i < 2; ++i) {
        int idx = i * 256 + tid;
        int r = idx >> 3;
        int ck = (idx & 7) ^ (r & 7) ^ (((r >> 3) & 1) << 2);
        __builtin_amdgcn_global_load_lds((const as1_uint*)(Kp + (size_t)(kvn + r) * HD + ck * 8),
                                         (as3_uint*)(Kl[cur ^ 1] + idx * 8), 16, 0, 0);
        __builtin_amdgcn_global_load_lds((const as1_uint*)(Vp + (size_t)r * S_LEN + kvn + (idx & 7) * 8),
                                         (as3_uint*)(Vl[cur ^ 1] + idx * 8), 16, 0, 0);
      }
    }

    const bool diag = (t == qidx);
    __builtin_amdgcn_s_setprio(1);
#pragma unroll
    for (int g = 0; g < 4; ++g) {
      const unsigned short* kp = Kl[cur] + (g * 16 + lw) * 64;
      const int c0 = quad ^ swk;
      bf16x8 kf0 = *(const bf16x8*)(kp + (c0 * 8));
      bf16x8 kf1 = *(const bf16x8*)(kp + ((c0 ^ 4) * 8));

      f32x4 s = (f32x4){0.f, 0.f, 0.f, 0.f};
      s = __builtin_amdgcn_mfma_f32_16x16x32_bf16(kf0, aq[0], s, 0, 0, 0);
      s = __builtin_amdgcn_mfma_f32_16x16x32_bf16(kf1, aq[1], s, 0, 0, 0);
      if (diag) {
#pragma unroll
        for (int r = 0; r < 4; ++r) {
          float e = __builtin_amdgcn_exp2f(s[r]);
          s[r] = (kv + g * 16 + quad * 4 + r > qr) ? 0.f : e;
        }
      } else {
#pragma unroll
        for (int r = 0; r < 4; ++r) s[r] = __builtin_amdgcn_exp2f(s[r]);
      }
      u32x2 pk;
      pk[0] = (fbits(s[1]) & 0xFFFF0000u) | (fbits(s[0]) >> 16);
      pk[1] = (fbits(s[3]) & 0xFFFF0000u) | (fbits(s[2]) >> 16);
      u16x4 pf = __builtin_bit_cast(u16x4, pk);

      // V fragment: 8B unit p8 = (4g+quad)^lw (global-baked swizzle) ->
      // 16-lane quad-phase covers all 32 banks exactly once.
      const int p8 = (4 * g + quad) ^ lw;
#pragma unroll
      for (int dg = 0; dg < 4; ++dg) {
        u16x4 vf = *(const u16x4*)(Vl[cur] + (dg * 16 + lw) * 64 + p8 * 4);
        accO[dg] = mfma16(pf, vf, accO[dg]);
      }
      accL = mfma16(pf, ones4, accL);
    }
    __builtin_amdgcn_s_setprio(0);
  }

  float* op = out + ((size_t)b * S_LEN + qbase + wave * 16 + quad * 4) * DM + h * HD + lw;
#pragma unroll
  for (int r = 0; r < 4; ++r) {
    float inv = 1.0f / accL[r];
#pragma unroll
    for (int dg = 0; dg < 4; ++dg) op[(size_t)r * DM + dg * 16] = accO[dg][r] * inv;
  }
}

extern "C" void kernel_launch(void* const* d_in, const int* in_sizes, int n_in,
                              void* d_out, int out_size, void* d_ws, size_t ws_size,
                              hipStream_t stream) {
  const float* x = (const float*)d_in[0];
  const float* Wq = (const float*)d_in[1];
  const float* bq = (const float*)d_in[2];
  const float* Wk = (const float*)d_in[3];
  const float* bk = (const float*)d_in[4];
  const float* Wv = (const float*)d_in[5];
  const float* bv = (const float*)d_in[6];
  float* out = (float*)d_out;

  char* ws = (char*)d_ws;
  unsigned short* xb = (unsigned short*)(ws + 0);          // 16 MB: X bf16 (8192,1024)
  unsigned short* wt = (unsigned short*)(ws + 16777216);   // 6 MB: Wq/Wk/Wv^T bf16
  unsigned short* qb = (unsigned short*)(ws + 23068672);   // 16 MB: Q*scale (B,H,S,64)
  unsigned short* kb = (unsigned short*)(ws + 39845888);   // 16 MB: K (B,H,S,64)
  unsigned short* vt = (unsigned short*)(ws + 56623104);   // 16 MB: V^T swizzled (B,H,64,S)

  // one-time: allow 144 KB dynamic LDS for qkv_gemm (runs on first invocation
  // only -- keeps the per-iteration host path free of runtime-attr calls)
  static bool qkv_attr_once = []() {
    hipFuncSetAttribute((const void*)qkv_gemm,
                        hipFuncAttributeMaxDynamicSharedMemorySize, QKV_LDS_BYTES);
    return true;
  }();
  (void)qkv_attr_once;

  hipLaunchKernelGGL(cvt_all, dim3(7168), dim3(256), 0, stream, x, xb, Wq, Wk, Wv, wt);
  hipLaunchKernelGGL(qkv_gemm, dim3(32, 8, 3), dim3(512), QKV_LDS_BYTES, stream,
                     xb, wt, bq, bk, bv, qb, kb, vt);
  hipLaunchKernelGGL(attn, dim3(2048), dim3(256), 0, stream, qb, kb, vt, out);
}

// Round 7
// 200.898 us; speedup vs baseline: 1.0159x; 1.0159x over previous
//
#include <hip/hip_runtime.h>

typedef __bf16 bf16x8 __attribute__((ext_vector_type(8)));
typedef __bf16 bf16x4 __attribute__((ext_vector_type(4)));
typedef short s16x4 __attribute__((ext_vector_type(4)));
typedef float f32x4 __attribute__((ext_vector_type(4)));
typedef unsigned short u16x8 __attribute__((ext_vector_type(8)));
typedef unsigned short u16x4 __attribute__((ext_vector_type(4)));
typedef unsigned int u32x2 __attribute__((ext_vector_type(2)));
typedef unsigned int u32x4 __attribute__((ext_vector_type(4)));
typedef unsigned int __attribute__((address_space(1))) as1_uint;
typedef unsigned int __attribute__((address_space(3))) as3_uint;

#define S_LEN 2048
#define NB 4
#define NH 16
#define HD 64
#define DM 1024

// 0.125 (1/sqrt(64)) * log2(e): Q is pre-scaled so attn does exp2 directly.
#define Q_SCALE 0.18033688011112042f

__device__ __forceinline__ unsigned short f2bf(float f) {
  union { float f; unsigned int u; } v; v.f = f;
  unsigned int r = v.u + 0x7fffu + ((v.u >> 16) & 1u);
  return (unsigned short)(r >> 16);
}

__device__ __forceinline__ unsigned int fbits(float f) {
  union { float f; unsigned int u; } v; v.f = f;
  return v.u;
}

__device__ __forceinline__ f32x4 mfma32(bf16x8 a, bf16x8 b, f32x4 c) {
  return __builtin_amdgcn_mfma_f32_16x16x32_bf16(a, b, c, 0, 0, 0);
}

// ---------- kernel 1: fused conversions ----------
// blocks [0,4096): X fp32 -> bf16 (layout preserved, 8192x1024)
// blocks [4096,7168): W (K,N) fp32 -> WT (N,K) bf16 for q/k/v
__global__ __launch_bounds__(256) void cvt_all(const float* __restrict__ x,
                                               unsigned short* __restrict__ xb,
                                               const float* __restrict__ Wq,
                                               const float* __restrict__ Wk,
                                               const float* __restrict__ Wv,
                                               unsigned short* __restrict__ wt) {
  __shared__ float tile[32][33];
  const int bid = blockIdx.x;
  if (bid < 4096) {
    int i = (bid * 256 + threadIdx.x) * 8;
    f32x4 a = *(const f32x4*)(x + i);
    f32x4 b = *(const f32x4*)(x + i + 4);
    u16x8 o;
    o[0] = f2bf(a[0]); o[1] = f2bf(a[1]); o[2] = f2bf(a[2]); o[3] = f2bf(a[3]);
    o[4] = f2bf(b[0]); o[5] = f2bf(b[1]); o[6] = f2bf(b[2]); o[7] = f2bf(b[3]);
    *(u16x8*)(xb + i) = o;
  } else {
    const int r = bid - 4096;
    const int z = r >> 10;
    const int rr = r & 1023;
    const float* W = (z == 0) ? Wq : (z == 1) ? Wk : Wv;
    unsigned short* WT = wt + (size_t)z * DM * DM;
    int tx = threadIdx.x & 31, ty = threadIdx.x >> 5;
    int k0 = (rr & 31) * 32, n0 = (rr >> 5) * 32;
#pragma unroll
    for (int i = 0; i < 4; ++i)
      tile[ty + 8 * i][tx] = W[(size_t)(k0 + ty + 8 * i) * DM + n0 + tx];
    __syncthreads();
#pragma unroll
    for (int i = 0; i < 4; ++i)
      WT[(size_t)(n0 + ty + 8 * i) * DM + k0 + tx] = f2bf(tile[tx][ty + 8 * i]);
  }
}

// ---------- kernel 2: QKV GEMM: Y = Xb @ W + b ----------
// 256x128 tile, BK=64, 8 waves, TRIPLE-buffered LDS, prefetch distance 2,
// counted vmcnt (never 0 in steady state). One raw barrier per K-tile.
// z=0 -> Q*Q_SCALE (B,H,S,HD) bf16 ; z=1 -> K (B,H,S,HD) bf16
// z=2 -> V^T (B,H,64,S) bf16 with a 16B-unit swizzle baked into the global
//        layout: within each 64-seq window, unit16' = unit16 ^ (d&7). attn
//        stages V LINEARLY (gload_lds) and reads PV's bf16x8 B-fragment as a
//        single aligned 16B ds_read at the swizzled unit -> min bank phases.
#define QKV_LDS_BYTES 147456  // 3 * (256*64 + 128*64) * 2
__global__ __launch_bounds__(512, 2) void qkv_gemm(const unsigned short* __restrict__ xb,
                                                   const unsigned short* __restrict__ wt,
                                                   const float* __restrict__ bq,
                                                   const float* __restrict__ bk,
                                                   const float* __restrict__ bv,
                                                   unsigned short* __restrict__ qo,
                                                   unsigned short* __restrict__ ko,
                                                   unsigned short* __restrict__ vto) {
  extern __shared__ char smem_dyn[];
  unsigned short* As = (unsigned short*)smem_dyn;             // 3 x 256x64
  unsigned short* Bs = As + 3 * 256 * 64;                     // 3 x 128x64
  const int z = blockIdx.z;
  const unsigned short* WT = wt + (size_t)z * DM * DM;
  const float* bias = (z == 0) ? bq : (z == 1) ? bk : bv;
  const int m0 = blockIdx.x * 256;
  const int n0 = blockIdx.y * 128;
  const int tid = threadIdx.x;
  const int wave = tid >> 6, lane = tid & 63, quad = lane >> 4, lw = lane & 15;
  const int wm = (wave >> 1) * 64, wn = (wave & 1) * 64;

  f32x4 acc[4][4];
#pragma unroll
  for (int mt = 0; mt < 4; ++mt)
#pragma unroll
    for (int nt = 0; nt < 4; ++nt) acc[mt][nt] = (f32x4){0.f, 0.f, 0.f, 0.f};

  auto stage = [&](int tile) {
    const int kt = tile * 64;
    const int bsel = tile % 3;
    unsigned short* Ad = As + bsel * (256 * 64);
    unsigned short* Bd = Bs + bsel * (128 * 64);
#pragma unroll
    for (int i = 0; i < 4; ++i) {
      int c = i * 512 + tid;
      int row = c >> 3, scn = (c & 7) ^ (row & 7);
      __builtin_amdgcn_global_load_lds((const as1_uint*)(xb + (size_t)(m0 + row) * DM + kt + scn * 8),
                                       (as3_uint*)(Ad + c * 8), 16, 0, 0);
    }
#pragma unroll
    for (int i = 0; i < 2; ++i) {
      int c = i * 512 + tid;
      int row = c >> 3, scn = (c & 7) ^ (row & 7);
      __builtin_amdgcn_global_load_lds((const as1_uint*)(WT + (size_t)(n0 + row) * DM + kt + scn * 8),
                                       (as3_uint*)(Bd + c * 8), 16, 0, 0);
    }
  };

  stage(0);
  stage(1);
  asm volatile("s_waitcnt vmcnt(6)" ::: "memory");
  __builtin_amdgcn_s_barrier();
  asm volatile("" ::: "memory");

#pragma unroll
  for (int t = 0; t < 16; ++t) {
    if (t + 2 < 16) stage(t + 2);

    const unsigned short* Ab = As + (t % 3) * (256 * 64);
    const unsigned short* Bb = Bs + (t % 3) * (128 * 64);
    bf16x8 af[2][4], bfq[2][4];
#pragma unroll
    for (int k = 0; k < 2; ++k) {
#pragma unroll
      for (int mt = 0; mt < 4; ++mt) {
        int r = wm + mt * 16 + lw;
        af[k][mt] = *(const bf16x8*)(Ab + r * 64 + (((k * 4 + quad) ^ (r & 7)) * 8));
      }
#pragma unroll
      for (int nt = 0; nt < 4; ++nt) {
        int r = wn + nt * 16 + lw;
        bfq[k][nt] = *(const bf16x8*)(Bb + r * 64 + (((k * 4 + quad) ^ (r & 7)) * 8));
      }
    }
#pragma unroll
    for (int k = 0; k < 2; ++k)
#pragma unroll
      for (int mt = 0; mt < 4; ++mt)
#pragma unroll
        for (int nt = 0; nt < 4; ++nt)
          acc[mt][nt] = __builtin_amdgcn_mfma_f32_16x16x32_bf16(af[k][mt], bfq[k][nt], acc[mt][nt], 0, 0, 0);

    if (t < 15) {
      if (t < 14) asm volatile("s_waitcnt vmcnt(6)" ::: "memory");
      else        asm volatile("s_waitcnt vmcnt(0)" ::: "memory");
      __builtin_amdgcn_s_barrier();
      asm volatile("" ::: "memory");
    }
  }

  float bias4[4];
#pragma unroll
  for (int nt = 0; nt < 4; ++nt) bias4[nt] = bias[n0 + wn + nt * 16 + lw];

  if (z < 2) {
    unsigned short* dst = (z == 0) ? qo : ko;
    const float sc = (z == 0) ? Q_SCALE : 1.0f;
#pragma unroll
    for (int mt = 0; mt < 4; ++mt) {
#pragma unroll
      for (int nt = 0; nt < 4; ++nt) {
        int n = n0 + wn + nt * 16 + lw;
        int h = n >> 6, d = n & 63;
#pragma unroll
        for (int r = 0; r < 4; ++r) {
          int m = m0 + wm + mt * 16 + quad * 4 + r;
          int b = m >> 11, s = m & 2047;
          dst[((size_t)(b * NH + h) * S_LEN + s) * HD + d] = f2bf((acc[mt][nt][r] + bias4[nt]) * sc);
        }
      }
    }
  } else {
#pragma unroll
    for (int mt = 0; mt < 4; ++mt) {
#pragma unroll
      for (int nt = 0; nt < 4; ++nt) {
        int n = n0 + wn + nt * 16 + lw;
        int h = n >> 6, d = n & 63;
        int mb = m0 + wm + mt * 16 + quad * 4;
        int b = mb >> 11, s = mb & 2047;
        u16x4 pk;
#pragma unroll
        for (int r = 0; r < 4; ++r) pk[r] = f2bf(acc[mt][nt][r] + bias4[nt]);
        // 16B-unit swizzle within each 64-seq window: unit16' = unit16 ^ (d&7)
        int us = (s & ~63) | ((((s >> 3) & 7) ^ (d & 7)) << 3) | (s & 7);
        *(u16x4*)(vto + ((size_t)(b * NH + h) * HD + d) * S_LEN + us) = pk;
      }
    }
  }
}

// ---------- kernel 3: causal flash attention, all-K=32 MFMA ------------
// One 64-q-row strip per block (2048 blocks), LPT dispatch, XCD affinity.
// K+V double-buffered LDS (32 KB -> 5 blocks/CU).
// PV at full rate: K rows are PERMUTED at staging (global source row
// gsrc = (p&32)|(((p>>2)&3)<<3)|(((p>>4)&1)<<2)|(p&3)) so that per 32-kv
// sub-block, S^T MFMA #1 (LDS rows gp*32+lw) yields kv rows 8q+r and #2
// (rows gp*32+16+lw) yields 8q+4+r. Concatenating their bf16-packed outputs
// is EXACTLY the 16x16x32 A-fragment (k = quad*8+j) -- PV and accL run as
// mfma_f32_16x16x32_bf16 with zero cross-lane traffic.
// Chunk swizzle (round-6 bug fixed): staging uses ck = (idx&7)^(p&7) ONLY;
// feature chunk f of any row p lives at LDS chunk f^(p&7), p&7 = lw&7 for
// every read row. Reads: lo features at c0 = (quad^(lw&7))*8, hi at c0^32 --
// identical involution on both sides (rule #21), same for both row groups.
// VALU cut: tile loop unrolled x2 with LITERAL buffer index, masked diagonal
// tile peeled out, all LDS addresses hoisted per-lane.
__global__ __launch_bounds__(256, 5) void attn(const unsigned short* __restrict__ Qb,
                                               const unsigned short* __restrict__ Kb,
                                               const unsigned short* __restrict__ Vtb,
                                               float* __restrict__ out) {
  const int flat = blockIdx.x;
  const int bh_lo = flat & 7;          // XCD affinity
  const int rest = flat >> 3;
  const int qidx = 31 - (rest >> 3);   // descending strip length (LPT)
  const int bh_hi = rest & 7;
  const int bh = bh_lo | (bh_hi << 3);
  const int b = bh >> 4, h = bh & 15;
  const int tid = threadIdx.x;
  const int wave = tid >> 6, lane = tid & 63;
  const int quad = lane >> 4, lw = lane & 15;
  const unsigned short* Qp = Qb + (size_t)bh * S_LEN * HD;
  const unsigned short* Kp = Kb + (size_t)bh * S_LEN * HD;
  const unsigned short* Vp = Vtb + (size_t)bh * HD * S_LEN;

  __shared__ __align__(16) unsigned short Kl[2][64 * 64];
  __shared__ __align__(16) unsigned short Vl[2][64 * 64];

  // Q fragments (B-operand: n=qrow=lane&15, k=quad*8+j)
  const int qbase = qidx * 64;
  bf16x8 aq[2];
#pragma unroll
  for (int kc = 0; kc < 2; ++kc)
    aq[kc] = *(const bf16x8*)(Qp + (size_t)(qbase + wave * 16 + lw) * HD + kc * 32 + quad * 8);

  u16x8 one8u;
#pragma unroll
  for (int i = 0; i < 8; ++i) one8u[i] = 0x3F80;
  const bf16x8 ones8 = __builtin_bit_cast(bf16x8, one8u);

  f32x4 accO[4];
  f32x4 accL = (f32x4){0.f, 0.f, 0.f, 0.f};
#pragma unroll
  for (int dg = 0; dg < 4; ++dg) accO[dg] = (f32x4){0.f, 0.f, 0.f, 0.f};

  const int qr = qbase + wave * 16 + lw;
  const int T = qidx + 1;

  // hoisted per-lane constants
  const int c0 = (quad ^ (lw & 7)) * 8;   // K chunk: lo features; hi = c0 ^ 32
  int w8[2];
#pragma unroll
  for (int gp = 0; gp < 2; ++gp) w8[gp] = ((gp * 4 + quad) ^ (lw & 7)) * 8;

  // staging offsets (per-lane invariant)
  int kOff[2], vOff[2], dOff[2];
#pragma unroll
  for (int i = 0; i < 2; ++i) {
    int idx = i * 256 + tid;
    int p = idx >> 3;
    int gsrc = (p & 32) | (((p >> 2) & 3) << 3) | (((p >> 4) & 1) << 2) | (p & 3);
    int ck = (idx & 7) ^ (p & 7);
    kOff[i] = gsrc * HD + ck * 8;
    vOff[i] = p * S_LEN + (idx & 7) * 8;
    dOff[i] = idx * 8;
  }

  auto stage = [&](int kvn, int buf) {
#pragma unroll
    for (int i = 0; i < 2; ++i) {
      __builtin_amdgcn_global_load_lds((const as1_uint*)(Kp + (size_t)kvn * HD + kOff[i]),
                                       (as3_uint*)(&Kl[buf][dOff[i]]), 16, 0, 0);
      __builtin_amdgcn_global_load_lds((const as1_uint*)(Vp + (size_t)kvn + vOff[i]),
                                       (as3_uint*)(&Vl[buf][dOff[i]]), 16, 0, 0);
    }
  };

  // tile body; cur/mask/pref are call-site literals
  auto body = [&](int t, int cur, bool mask, bool pref) {
    const int kv = t * 64;
    __syncthreads();  // buf[cur] staged; all waves done reading buf[cur^1]
    if (pref) stage(kv + 64, cur ^ 1);

    const unsigned short* kb = Kl[cur] + lw * 64;
    const unsigned short* vb = Vl[cur] + lw * 64;
    __builtin_amdgcn_s_setprio(1);
#pragma unroll
    for (int gp = 0; gp < 2; ++gp) {
      const unsigned short* kg = kb + gp * 2048;
      bf16x8 k00 = *(const bf16x8*)(kg + c0);                 // rows lw,    features lo
      bf16x8 k01 = *(const bf16x8*)(kg + (c0 ^ 32));          // rows lw,    features hi
      bf16x8 k10 = *(const bf16x8*)(kg + 1024 + c0);          // rows lw+16, features lo
      bf16x8 k11 = *(const bf16x8*)(kg + 1024 + (c0 ^ 32));   // rows lw+16, features hi

      f32x4 s0 = (f32x4){0.f, 0.f, 0.f, 0.f};
      f32x4 s1 = (f32x4){0.f, 0.f, 0.f, 0.f};
      s0 = mfma32(k00, aq[0], s0);
      s0 = mfma32(k01, aq[1], s0);
      s1 = mfma32(k10, aq[0], s1);
      s1 = mfma32(k11, aq[1], s1);

      if (mask) {
        const int kvb = kv + gp * 32 + 8 * quad;
#pragma unroll
        for (int r = 0; r < 4; ++r) {
          float e0 = __builtin_amdgcn_exp2f(s0[r]);
          float e1 = __builtin_amdgcn_exp2f(s1[r]);
          s0[r] = (kvb + r > qr) ? 0.f : e0;
          s1[r] = (kvb + 4 + r > qr) ? 0.f : e1;
        }
      } else {
#pragma unroll
        for (int r = 0; r < 4; ++r) {
          s0[r] = __builtin_amdgcn_exp2f(s0[r]);
          s1[r] = __builtin_amdgcn_exp2f(s1[r]);
        }
      }
      // pack to x32 A-fragment: slots j=0..3 <- s0 (kv 8q+r), j=4..7 <- s1 (kv 8q+4+r)
      u32x4 pw;
      pw[0] = (fbits(s0[1]) & 0xFFFF0000u) | (fbits(s0[0]) >> 16);
      pw[1] = (fbits(s0[3]) & 0xFFFF0000u) | (fbits(s0[2]) >> 16);
      pw[2] = (fbits(s1[1]) & 0xFFFF0000u) | (fbits(s1[0]) >> 16);
      pw[3] = (fbits(s1[3]) & 0xFFFF0000u) | (fbits(s1[2]) >> 16);
      bf16x8 af = __builtin_bit_cast(bf16x8, pw);

#pragma unroll
      for (int dg = 0; dg < 4; ++dg) {
        bf16x8 vf = *(const bf16x8*)(vb + dg * 1024 + w8[gp]);
        accO[dg] = mfma32(af, vf, accO[dg]);
      }
      accL = mfma32(af, ones8, accL);
    }
    __builtin_amdgcn_s_setprio(0);
  };

  // prologue: stage tile 0 into buffer 0
  stage(0, 0);

  int t = 0;
  const int nmain = T - 1;  // tiles without causal mask
  for (; t + 1 < nmain; t += 2) {
    body(t, 0, false, true);
    body(t + 1, 1, false, true);
  }
  if (t < nmain) { body(t, 0, false, true); ++t; }
  if (t & 1) body(t, 1, true, false);
  else       body(t, 0, true, false);

  float* op = out + ((size_t)b * S_LEN + qbase + wave * 16 + quad * 4) * DM + h * HD + lw;
#pragma unroll
  for (int r = 0; r < 4; ++r) {
    float inv = 1.0f / accL[r];
#pragma unroll
    for (int dg = 0; dg < 4; ++dg) op[(size_t)r * DM + dg * 16] = accO[dg][r] * inv;
  }
}

extern "C" void kernel_launch(void* const* d_in, const int* in_sizes, int n_in,
                              void* d_out, int out_size, void* d_ws, size_t ws_size,
                              hipStream_t stream) {
  const float* x = (const float*)d_in[0];
  const float* Wq = (const float*)d_in[1];
  const float* bq = (const float*)d_in[2];
  const float* Wk = (const float*)d_in[3];
  const float* bk = (const float*)d_in[4];
  const float* Wv = (const float*)d_in[5];
  const float* bv = (const float*)d_in[6];
  float* out = (float*)d_out;

  char* ws = (char*)d_ws;
  unsigned short* xb = (unsigned short*)(ws + 0);          // 16 MB: X bf16 (8192,1024)
  unsigned short* wt = (unsigned short*)(ws + 16777216);   // 6 MB: Wq/Wk/Wv^T bf16
  unsigned short* qb = (unsigned short*)(ws + 23068672);   // 16 MB: Q*scale (B,H,S,64)
  unsigned short* kb = (unsigned short*)(ws + 39845888);   // 16 MB: K (B,H,S,64)
  unsigned short* vt = (unsigned short*)(ws + 56623104);   // 16 MB: V^T swizzled (B,H,64,S)

  static bool qkv_attr_once = []() {
    hipFuncSetAttribute((const void*)qkv_gemm,
                        hipFuncAttributeMaxDynamicSharedMemorySize, QKV_LDS_BYTES);
    return true;
  }();
  (void)qkv_attr_once;

  hipLaunchKernelGGL(cvt_all, dim3(7168), dim3(256), 0, stream, x, xb, Wq, Wk, Wv, wt);
  hipLaunchKernelGGL(qkv_gemm, dim3(32, 8, 3), dim3(512), QKV_LDS_BYTES, stream,
                     xb, wt, bq, bk, bv, qb, kb, vt);
  hipLaunchKernelGGL(attn, dim3(2048), dim3(256), 0, stream, qb, kb, vt, out);
}

// Round 8
// 193.480 us; speedup vs baseline: 1.0549x; 1.0383x over previous
//
#include <hip/hip_runtime.h>

typedef __bf16 bf16x8 __attribute__((ext_vector_type(8)));
typedef __bf16 bf16x4 __attribute__((ext_vector_type(4)));
typedef short s16x4 __attribute__((ext_vector_type(4)));
typedef float f32x4 __attribute__((ext_vector_type(4)));
typedef unsigned short u16x8 __attribute__((ext_vector_type(8)));
typedef unsigned short u16x4 __attribute__((ext_vector_type(4)));
typedef unsigned int u32x2 __attribute__((ext_vector_type(2)));
typedef unsigned int u32x4 __attribute__((ext_vector_type(4)));
typedef unsigned int __attribute__((address_space(1))) as1_uint;
typedef unsigned int __attribute__((address_space(3))) as3_uint;

#define S_LEN 2048
#define NB 4
#define NH 16
#define HD 64
#define DM 1024

// 0.125 (1/sqrt(64)) * log2(e): Q is pre-scaled so attn does exp2 directly.
#define Q_SCALE 0.18033688011112042f

__device__ __forceinline__ unsigned short f2bf(float f) {
  union { float f; unsigned int u; } v; v.f = f;
  unsigned int r = v.u + 0x7fffu + ((v.u >> 16) & 1u);
  return (unsigned short)(r >> 16);
}

__device__ __forceinline__ unsigned int fbits(float f) {
  union { float f; unsigned int u; } v; v.f = f;
  return v.u;
}

__device__ __forceinline__ f32x4 mfma32(bf16x8 a, bf16x8 b, f32x4 c) {
  return __builtin_amdgcn_mfma_f32_16x16x32_bf16(a, b, c, 0, 0, 0);
}

// ---------- kernel 1: fused conversions ----------
// blocks [0,4096): X fp32 -> bf16 (layout preserved, 8192x1024)
// blocks [4096,7168): W (K,N) fp32 -> WT (N,K) bf16 for q/k/v
__global__ __launch_bounds__(256) void cvt_all(const float* __restrict__ x,
                                               unsigned short* __restrict__ xb,
                                               const float* __restrict__ Wq,
                                               const float* __restrict__ Wk,
                                               const float* __restrict__ Wv,
                                               unsigned short* __restrict__ wt) {
  __shared__ float tile[32][33];
  const int bid = blockIdx.x;
  if (bid < 4096) {
    int i = (bid * 256 + threadIdx.x) * 8;
    f32x4 a = *(const f32x4*)(x + i);
    f32x4 b = *(const f32x4*)(x + i + 4);
    u16x8 o;
    o[0] = f2bf(a[0]); o[1] = f2bf(a[1]); o[2] = f2bf(a[2]); o[3] = f2bf(a[3]);
    o[4] = f2bf(b[0]); o[5] = f2bf(b[1]); o[6] = f2bf(b[2]); o[7] = f2bf(b[3]);
    *(u16x8*)(xb + i) = o;
  } else {
    const int r = bid - 4096;
    const int z = r >> 10;
    const int rr = r & 1023;
    const float* W = (z == 0) ? Wq : (z == 1) ? Wk : Wv;
    unsigned short* WT = wt + (size_t)z * DM * DM;
    int tx = threadIdx.x & 31, ty = threadIdx.x >> 5;
    int k0 = (rr & 31) * 32, n0 = (rr >> 5) * 32;
#pragma unroll
    for (int i = 0; i < 4; ++i)
      tile[ty + 8 * i][tx] = W[(size_t)(k0 + ty + 8 * i) * DM + n0 + tx];
    __syncthreads();
#pragma unroll
    for (int i = 0; i < 4; ++i)
      WT[(size_t)(n0 + ty + 8 * i) * DM + k0 + tx] = f2bf(tile[tx][ty + 8 * i]);
  }
}

// ---------- kernel 2: QKV GEMM: Y = Xb @ W + b ----------
// LDS-BW-optimized config (round-7 diagnosis: LDS-bandwidth-bound at 917 TF):
// 256x128 tile, BK=32, 4 waves (2M x 2N, each wave owns 128x64), TRIPLE-
// buffered LDS (72 KB -> TWO blocks/CU, 8 waves: barrier stalls of one block
// overlap the other block's MFMA), prefetch distance 2, counted vmcnt(6)
// (never 0 in steady state), one raw barrier per K-tile.
// Wave-level operand duplication drops from A:x2/B:x4 to A:x2/B:x2 -> block
// LDS read traffic per output -18%.
// Chunk swizzle for 64B rows (both-sides involution): f(row)=(row&3)^((row>>2)&3);
// stage source chunk (c&3)^f(row); fragment read chunk quad^f(r). Worst-case
// 2-way bank alias (free, m136).
// z=0 -> Q*Q_SCALE (B,H,S,HD) bf16 ; z=1 -> K (B,H,S,HD) bf16
// z=2 -> V^T (B,H,64,S) bf16 with a 16B-unit swizzle baked into the global
//        layout: within each 64-seq window, unit16' = unit16 ^ (d&7) (attn
//        stages V linearly and reads conflict-free).
#define QKV_LDS_BYTES 73728  // 3 * (256*32 + 128*32) * 2
__global__ __launch_bounds__(256, 2) void qkv_gemm(const unsigned short* __restrict__ xb,
                                                   const unsigned short* __restrict__ wt,
                                                   const float* __restrict__ bq,
                                                   const float* __restrict__ bk,
                                                   const float* __restrict__ bv,
                                                   unsigned short* __restrict__ qo,
                                                   unsigned short* __restrict__ ko,
                                                   unsigned short* __restrict__ vto) {
  extern __shared__ char smem_dyn[];
  unsigned short* As = (unsigned short*)smem_dyn;             // 3 x 256x32
  unsigned short* Bs = As + 3 * 256 * 32;                     // 3 x 128x32
  const int z = blockIdx.z;
  const unsigned short* WT = wt + (size_t)z * DM * DM;
  const float* bias = (z == 0) ? bq : (z == 1) ? bk : bv;
  const int m0 = blockIdx.x * 256;
  const int n0 = blockIdx.y * 128;
  const int tid = threadIdx.x;
  const int wave = tid >> 6, lane = tid & 63, quad = lane >> 4, lw = lane & 15;
  const int wm = (wave >> 1) * 128, wn = (wave & 1) * 64;

  f32x4 acc[8][4];
#pragma unroll
  for (int mt = 0; mt < 8; ++mt)
#pragma unroll
    for (int nt = 0; nt < 4; ++nt) acc[mt][nt] = (f32x4){0.f, 0.f, 0.f, 0.f};

  // ---- staging: 6 global_load_lds (16B) per thread per K-tile ----
  auto stage = [&](int tile) {
    const int kt = tile * 32;
    const int bsel = tile % 3;
    unsigned short* Ad = As + bsel * (256 * 32);
    unsigned short* Bd = Bs + bsel * (128 * 32);
#pragma unroll
    for (int i = 0; i < 4; ++i) {
      int c = i * 256 + tid;
      int row = c >> 2, scn = (c & 3) ^ (row & 3) ^ ((row >> 2) & 3);
      __builtin_amdgcn_global_load_lds((const as1_uint*)(xb + (size_t)(m0 + row) * DM + kt + scn * 8),
                                       (as3_uint*)(Ad + c * 8), 16, 0, 0);
    }
#pragma unroll
    for (int i = 0; i < 2; ++i) {
      int c = i * 256 + tid;
      int row = c >> 2, scn = (c & 3) ^ (row & 3) ^ ((row >> 2) & 3);
      __builtin_amdgcn_global_load_lds((const as1_uint*)(WT + (size_t)(n0 + row) * DM + kt + scn * 8),
                                       (as3_uint*)(Bd + c * 8), 16, 0, 0);
    }
  };

  // prologue: tiles 0 and 1 in flight; wait for tile 0 (6 loads still out)
  stage(0);
  stage(1);
  asm volatile("s_waitcnt vmcnt(6)" ::: "memory");
  __builtin_amdgcn_s_barrier();
  asm volatile("" ::: "memory");

#pragma unroll
  for (int t = 0; t < 32; ++t) {
    if (t + 2 < 32) stage(t + 2);

    const unsigned short* Ab = As + (t % 3) * (256 * 32);
    const unsigned short* Bb = Bs + (t % 3) * (128 * 32);
    bf16x8 af[8], bfq[4];
#pragma unroll
    for (int mt = 0; mt < 8; ++mt) {
      int r = wm + mt * 16 + lw;
      af[mt] = *(const bf16x8*)(Ab + r * 32 + (((quad ^ (r & 3) ^ ((r >> 2) & 3))) * 8));
    }
#pragma unroll
    for (int nt = 0; nt < 4; ++nt) {
      int r = wn + nt * 16 + lw;
      bfq[nt] = *(const bf16x8*)(Bb + r * 32 + (((quad ^ (r & 3) ^ ((r >> 2) & 3))) * 8));
    }
#pragma unroll
    for (int mt = 0; mt < 8; ++mt)
#pragma unroll
      for (int nt = 0; nt < 4; ++nt)
        acc[mt][nt] = mfma32(af[mt], bfq[nt], acc[mt][nt]);

    if (t < 31) {
      if (t < 30) asm volatile("s_waitcnt vmcnt(6)" ::: "memory");
      else        asm volatile("s_waitcnt vmcnt(0)" ::: "memory");
      __builtin_amdgcn_s_barrier();
      asm volatile("" ::: "memory");
    }
  }

  float bias4[4];
#pragma unroll
  for (int nt = 0; nt < 4; ++nt) bias4[nt] = bias[n0 + wn + nt * 16 + lw];

  if (z < 2) {
    unsigned short* dst = (z == 0) ? qo : ko;
    const float sc = (z == 0) ? Q_SCALE : 1.0f;
#pragma unroll
    for (int mt = 0; mt < 8; ++mt) {
#pragma unroll
      for (int nt = 0; nt < 4; ++nt) {
        int n = n0 + wn + nt * 16 + lw;
        int h = n >> 6, d = n & 63;
#pragma unroll
        for (int r = 0; r < 4; ++r) {
          int m = m0 + wm + mt * 16 + quad * 4 + r;
          int b = m >> 11, s = m & 2047;
          dst[((size_t)(b * NH + h) * S_LEN + s) * HD + d] = f2bf((acc[mt][nt][r] + bias4[nt]) * sc);
        }
      }
    }
  } else {
#pragma unroll
    for (int mt = 0; mt < 8; ++mt) {
#pragma unroll
      for (int nt = 0; nt < 4; ++nt) {
        int n = n0 + wn + nt * 16 + lw;
        int h = n >> 6, d = n & 63;
        int mb = m0 + wm + mt * 16 + quad * 4;
        int b = mb >> 11, s = mb & 2047;
        u16x4 pk;
#pragma unroll
        for (int r = 0; r < 4; ++r) pk[r] = f2bf(acc[mt][nt][r] + bias4[nt]);
        // 16B-unit swizzle within each 64-seq window: unit16' = unit16 ^ (d&7)
        int us = (s & ~63) | ((((s >> 3) & 7) ^ (d & 7)) << 3) | (s & 7);
        *(u16x4*)(vto + ((size_t)(b * NH + h) * HD + d) * S_LEN + us) = pk;
      }
    }
  }
}

// ---------- kernel 3: causal flash attention, all-K=32 MFMA ------------
// One 64-q-row strip per block (2048 blocks), LPT dispatch, XCD affinity.
// K+V double-buffered LDS (32 KB -> 5 blocks/CU).
// PV at full rate: K rows are PERMUTED at staging (global source row
// gsrc = (p&32)|(((p>>2)&3)<<3)|(((p>>4)&1)<<2)|(p&3)) so that per 32-kv
// sub-block, S^T MFMA #1 (LDS rows gp*32+lw) yields kv rows 8q+r and #2
// (rows gp*32+16+lw) yields 8q+4+r. Concatenating their bf16-packed outputs
// is EXACTLY the 16x16x32 A-fragment (k = quad*8+j) -- PV and accL run as
// mfma_f32_16x16x32_bf16 with zero cross-lane traffic.
// Chunk swizzle: staging ck = (idx&7)^(p&7); reads at c0 = (quad^(lw&7))*8,
// hi at c0^32 -- identical involution both sides, same for both row groups.
// VALU cut: tile loop unrolled x2 with LITERAL buffer index, masked diagonal
// tile peeled out, all LDS addresses hoisted per-lane.
__global__ __launch_bounds__(256, 5) void attn(const unsigned short* __restrict__ Qb,
                                               const unsigned short* __restrict__ Kb,
                                               const unsigned short* __restrict__ Vtb,
                                               float* __restrict__ out) {
  const int flat = blockIdx.x;
  const int bh_lo = flat & 7;          // XCD affinity
  const int rest = flat >> 3;
  const int qidx = 31 - (rest >> 3);   // descending strip length (LPT)
  const int bh_hi = rest & 7;
  const int bh = bh_lo | (bh_hi << 3);
  const int b = bh >> 4, h = bh & 15;
  const int tid = threadIdx.x;
  const int wave = tid >> 6, lane = tid & 63;
  const int quad = lane >> 4, lw = lane & 15;
  const unsigned short* Qp = Qb + (size_t)bh * S_LEN * HD;
  const unsigned short* Kp = Kb + (size_t)bh * S_LEN * HD;
  const unsigned short* Vp = Vtb + (size_t)bh * HD * S_LEN;

  __shared__ __align__(16) unsigned short Kl[2][64 * 64];
  __shared__ __align__(16) unsigned short Vl[2][64 * 64];

  // Q fragments (B-operand: n=qrow=lane&15, k=quad*8+j)
  const int qbase = qidx * 64;
  bf16x8 aq[2];
#pragma unroll
  for (int kc = 0; kc < 2; ++kc)
    aq[kc] = *(const bf16x8*)(Qp + (size_t)(qbase + wave * 16 + lw) * HD + kc * 32 + quad * 8);

  u16x8 one8u;
#pragma unroll
  for (int i = 0; i < 8; ++i) one8u[i] = 0x3F80;
  const bf16x8 ones8 = __builtin_bit_cast(bf16x8, one8u);

  f32x4 accO[4];
  f32x4 accL = (f32x4){0.f, 0.f, 0.f, 0.f};
#pragma unroll
  for (int dg = 0; dg < 4; ++dg) accO[dg] = (f32x4){0.f, 0.f, 0.f, 0.f};

  const int qr = qbase + wave * 16 + lw;
  const int T = qidx + 1;

  // hoisted per-lane constants
  const int c0 = (quad ^ (lw & 7)) * 8;   // K chunk: lo features; hi = c0 ^ 32
  int w8[2];
#pragma unroll
  for (int gp = 0; gp < 2; ++gp) w8[gp] = ((gp * 4 + quad) ^ (lw & 7)) * 8;

  // staging offsets (per-lane invariant)
  int kOff[2], vOff[2], dOff[2];
#pragma unroll
  for (int i = 0; i < 2; ++i) {
    int idx = i * 256 + tid;
    int p = idx >> 3;
    int gsrc = (p & 32) | (((p >> 2) & 3) << 3) | (((p >> 4) & 1) << 2) | (p & 3);
    int ck = (idx & 7) ^ (p & 7);
    kOff[i] = gsrc * HD + ck * 8;
    vOff[i] = p * S_LEN + (idx & 7) * 8;
    dOff[i] = idx * 8;
  }

  auto stage = [&](int kvn, int buf) {
#pragma unroll
    for (int i = 0; i < 2; ++i) {
      __builtin_amdgcn_global_load_lds((const as1_uint*)(Kp + (size_t)kvn * HD + kOff[i]),
                                       (as3_uint*)(&Kl[buf][dOff[i]]), 16, 0, 0);
      __builtin_amdgcn_global_load_lds((const as1_uint*)(Vp + (size_t)kvn + vOff[i]),
                                       (as3_uint*)(&Vl[buf][dOff[i]]), 16, 0, 0);
    }
  };

  // tile body; cur/mask/pref are call-site literals
  auto body = [&](int t, int cur, bool mask, bool pref) {
    const int kv = t * 64;
    __syncthreads();  // buf[cur] staged; all waves done reading buf[cur^1]
    if (pref) stage(kv + 64, cur ^ 1);

    const unsigned short* kb = Kl[cur] + lw * 64;
    const unsigned short* vb = Vl[cur] + lw * 64;
    __builtin_amdgcn_s_setprio(1);
#pragma unroll
    for (int gp = 0; gp < 2; ++gp) {
      const unsigned short* kg = kb + gp * 2048;
      bf16x8 k00 = *(const bf16x8*)(kg + c0);                 // rows lw,    features lo
      bf16x8 k01 = *(const bf16x8*)(kg + (c0 ^ 32));          // rows lw,    features hi
      bf16x8 k10 = *(const bf16x8*)(kg + 1024 + c0);          // rows lw+16, features lo
      bf16x8 k11 = *(const bf16x8*)(kg + 1024 + (c0 ^ 32));   // rows lw+16, features hi

      f32x4 s0 = (f32x4){0.f, 0.f, 0.f, 0.f};
      f32x4 s1 = (f32x4){0.f, 0.f, 0.f, 0.f};
      s0 = mfma32(k00, aq[0], s0);
      s0 = mfma32(k01, aq[1], s0);
      s1 = mfma32(k10, aq[0], s1);
      s1 = mfma32(k11, aq[1], s1);

      if (mask) {
        const int kvb = kv + gp * 32 + 8 * quad;
#pragma unroll
        for (int r = 0; r < 4; ++r) {
          float e0 = __builtin_amdgcn_exp2f(s0[r]);
          float e1 = __builtin_amdgcn_exp2f(s1[r]);
          s0[r] = (kvb + r > qr) ? 0.f : e0;
          s1[r] = (kvb + 4 + r > qr) ? 0.f : e1;
        }
      } else {
#pragma unroll
        for (int r = 0; r < 4; ++r) {
          s0[r] = __builtin_amdgcn_exp2f(s0[r]);
          s1[r] = __builtin_amdgcn_exp2f(s1[r]);
        }
      }
      // pack to x32 A-fragment: slots j=0..3 <- s0 (kv 8q+r), j=4..7 <- s1 (kv 8q+4+r)
      u32x4 pw;
      pw[0] = (fbits(s0[1]) & 0xFFFF0000u) | (fbits(s0[0]) >> 16);
      pw[1] = (fbits(s0[3]) & 0xFFFF0000u) | (fbits(s0[2]) >> 16);
      pw[2] = (fbits(s1[1]) & 0xFFFF0000u) | (fbits(s1[0]) >> 16);
      pw[3] = (fbits(s1[3]) & 0xFFFF0000u) | (fbits(s1[2]) >> 16);
      bf16x8 af = __builtin_bit_cast(bf16x8, pw);

#pragma unroll
      for (int dg = 0; dg < 4; ++dg) {
        bf16x8 vf = *(const bf16x8*)(vb + dg * 1024 + w8[gp]);
        accO[dg] = mfma32(af, vf, accO[dg]);
      }
      accL = mfma32(af, ones8, accL);
    }
    __builtin_amdgcn_s_setprio(0);
  };

  // prologue: stage tile 0 into buffer 0
  stage(0, 0);

  int t = 0;
  const int nmain = T - 1;  // tiles without causal mask
  for (; t + 1 < nmain; t += 2) {
    body(t, 0, false, true);
    body(t + 1, 1, false, true);
  }
  if (t < nmain) { body(t, 0, false, true); ++t; }
  if (t & 1) body(t, 1, true, false);
  else       body(t, 0, true, false);

  float* op = out + ((size_t)b * S_LEN + qbase + wave * 16 + quad * 4) * DM + h * HD + lw;
#pragma unroll
  for (int r = 0; r < 4; ++r) {
    float inv = 1.0f / accL[r];
#pragma unroll
    for (int dg = 0; dg < 4; ++dg) op[(size_t)r * DM + dg * 16] = accO[dg][r] * inv;
  }
}

extern "C" void kernel_launch(void* const* d_in, const int* in_sizes, int n_in,
                              void* d_out, int out_size, void* d_ws, size_t ws_size,
                              hipStream_t stream) {
  const float* x = (const float*)d_in[0];
  const float* Wq = (const float*)d_in[1];
  const float* bq = (const float*)d_in[2];
  const float* Wk = (const float*)d_in[3];
  const float* bk = (const float*)d_in[4];
  const float* Wv = (const float*)d_in[5];
  const float* bv = (const float*)d_in[6];
  float* out = (float*)d_out;

  char* ws = (char*)d_ws;
  unsigned short* xb = (unsigned short*)(ws + 0);          // 16 MB: X bf16 (8192,1024)
  unsigned short* wt = (unsigned short*)(ws + 16777216);   // 6 MB: Wq/Wk/Wv^T bf16
  unsigned short* qb = (unsigned short*)(ws + 23068672);   // 16 MB: Q*scale (B,H,S,64)
  unsigned short* kb = (unsigned short*)(ws + 39845888);   // 16 MB: K (B,H,S,64)
  unsigned short* vt = (unsigned short*)(ws + 56623104);   // 16 MB: V^T swizzled (B,H,64,S)

  static bool qkv_attr_once = []() {
    hipFuncSetAttribute((const void*)qkv_gemm,
                        hipFuncAttributeMaxDynamicSharedMemorySize, QKV_LDS_BYTES);
    return true;
  }();
  (void)qkv_attr_once;

  hipLaunchKernelGGL(cvt_all, dim3(7168), dim3(256), 0, stream, x, xb, Wq, Wk, Wv, wt);
  hipLaunchKernelGGL(qkv_gemm, dim3(32, 8, 3), dim3(256), QKV_LDS_BYTES, stream,
                     xb, wt, bq, bk, bv, qb, kb, vt);
  hipLaunchKernelGGL(attn, dim3(2048), dim3(256), 0, stream, qb, kb, vt, out);
}

// Round 10
// 189.589 us; speedup vs baseline: 1.0765x; 1.0205x over previous
//
#include <hip/hip_runtime.h>

typedef __bf16 bf16x8 __attribute__((ext_vector_type(8)));
typedef float f32x4 __attribute__((ext_vector_type(4)));
typedef unsigned short u16x8 __attribute__((ext_vector_type(8)));
typedef unsigned short u16x4 __attribute__((ext_vector_type(4)));
typedef unsigned int u32x4 __attribute__((ext_vector_type(4)));
typedef unsigned int __attribute__((address_space(1))) as1_uint;
typedef unsigned int __attribute__((address_space(3))) as3_uint;

#define S_LEN 2048
#define NB 4
#define NH 16
#define HD 64
#define DM 1024

// 0.125 (1/sqrt(64)) * log2(e): Q is pre-scaled so attn does exp2 directly.
#define Q_SCALE 0.18033688011112042f

#define QKV_LDS_BYTES 147456  // 3 * (256*64 + 128*64) * 2

__device__ __forceinline__ unsigned short f2bf(float f) {
  union { float f; unsigned int u; } v; v.f = f;
  unsigned int r = v.u + 0x7fffu + ((v.u >> 16) & 1u);
  return (unsigned short)(r >> 16);
}

__device__ __forceinline__ unsigned int fbits(float f) {
  union { float f; unsigned int u; } v; v.f = f;
  return v.u;
}

__device__ __forceinline__ f32x4 mfma32(bf16x8 a, bf16x8 b, f32x4 c) {
  return __builtin_amdgcn_mfma_f32_16x16x32_bf16(a, b, c, 0, 0, 0);
}

// ---------- kernel 1: fused conversions ----------
// blocks [0,4096): X fp32 -> bf16 (layout preserved, 8192x1024)
// blocks [4096,7168): W (K,N) fp32 -> WT (N,K) bf16 for q/k/v
__global__ __launch_bounds__(256) void cvt_all(const float* __restrict__ x,
                                               unsigned short* __restrict__ xb,
                                               const float* __restrict__ Wq,
                                               const float* __restrict__ Wk,
                                               const float* __restrict__ Wv,
                                               unsigned short* __restrict__ wt) {
  __shared__ float tile[32][33];
  const int bid = blockIdx.x;
  if (bid < 4096) {
    int i = (bid * 256 + threadIdx.x) * 8;
    f32x4 a = *(const f32x4*)(x + i);
    f32x4 b = *(const f32x4*)(x + i + 4);
    u16x8 o;
    o[0] = f2bf(a[0]); o[1] = f2bf(a[1]); o[2] = f2bf(a[2]); o[3] = f2bf(a[3]);
    o[4] = f2bf(b[0]); o[5] = f2bf(b[1]); o[6] = f2bf(b[2]); o[7] = f2bf(b[3]);
    *(u16x8*)(xb + i) = o;
  } else {
    const int r = bid - 4096;
    const int z = r >> 10;
    const int rr = r & 1023;
    const float* W = (z == 0) ? Wq : (z == 1) ? Wk : Wv;
    unsigned short* WT = wt + (size_t)z * DM * DM;
    int tx = threadIdx.x & 31, ty = threadIdx.x >> 5;
    int k0 = (rr & 31) * 32, n0 = (rr >> 5) * 32;
#pragma unroll
    for (int i = 0; i < 4; ++i)
      tile[ty + 8 * i][tx] = W[(size_t)(k0 + ty + 8 * i) * DM + n0 + tx];
    __syncthreads();
#pragma unroll
    for (int i = 0; i < 4; ++i)
      WT[(size_t)(n0 + ty + 8 * i) * DM + k0 + tx] = f2bf(tile[tx][ty + 8 * i]);
  }
}

// ---------- kernel 2: QKV GEMM: Y = Xb @ W + b ----------
// R7-proven structure: 256x128 tile, BK=64, 8 waves (4Mx2N, 64x64/wave),
// TRIPLE-buffered LDS, prefetch distance 2, counted vmcnt(6) (never 0 in
// steady state), one raw barrier per K-tile.
// This round's probe: each K-tile's compute is split into two
// {ds_read k-half || stage-half -> setprio(1) 16xMFMA setprio(0)} phases.
// SAME barrier placement, SAME 6 vmem issues/thread/tile -> sync semantics
// identical to the verified R7 kernel; only in-region instruction order
// differs (zero new race surface).
// z=0 -> Q*Q_SCALE (B,H,S,HD) bf16 ; z=1 -> K (B,H,S,HD) bf16
// z=2 -> V^T (B,H,64,S) bf16 with a 16B-unit swizzle baked into the global
//        layout: within each 64-seq window, unit16' = unit16 ^ (d&7). attn
//        stages V LINEARLY (gload_lds) and reads PV's bf16x8 B-fragment as a
//        single aligned 16B ds_read at the swizzled unit -> min bank phases.
__global__ __launch_bounds__(512, 2) void qkv_gemm(const unsigned short* __restrict__ xb,
                                                   const unsigned short* __restrict__ wt,
                                                   const float* __restrict__ bq,
                                                   const float* __restrict__ bk,
                                                   const float* __restrict__ bv,
                                                   unsigned short* __restrict__ qo,
                                                   unsigned short* __restrict__ ko,
                                                   unsigned short* __restrict__ vto) {
  extern __shared__ char smem_dyn[];
  unsigned short* As = (unsigned short*)smem_dyn;             // 3 x 256x64
  unsigned short* Bs = As + 3 * 256 * 64;                     // 3 x 128x64
  const int z = blockIdx.z;
  const unsigned short* WT = wt + (size_t)z * DM * DM;
  const float* bias = (z == 0) ? bq : (z == 1) ? bk : bv;
  const int m0 = blockIdx.x * 256;
  const int n0 = blockIdx.y * 128;
  const int tid = threadIdx.x;
  const int wave = tid >> 6, lane = tid & 63, quad = lane >> 4, lw = lane & 15;
  const int wm = (wave >> 1) * 64, wn = (wave & 1) * 64;

  f32x4 acc[4][4];
#pragma unroll
  for (int mt = 0; mt < 4; ++mt)
#pragma unroll
    for (int nt = 0; nt < 4; ++nt) acc[mt][nt] = (f32x4){0.f, 0.f, 0.f, 0.f};

  auto stageA = [&](int tile) {  // 4 x 16B gload_lds: A half
    const int kt = tile * 64;
    unsigned short* Ad = As + (tile % 3) * (256 * 64);
#pragma unroll
    for (int i = 0; i < 4; ++i) {
      int c = i * 512 + tid;
      int row = c >> 3, scn = (c & 7) ^ (row & 7);
      __builtin_amdgcn_global_load_lds((const as1_uint*)(xb + (size_t)(m0 + row) * DM + kt + scn * 8),
                                       (as3_uint*)(Ad + c * 8), 16, 0, 0);
    }
  };
  auto stageB = [&](int tile) {  // 2 x 16B gload_lds: B half
    const int kt = tile * 64;
    unsigned short* Bd = Bs + (tile % 3) * (128 * 64);
#pragma unroll
    for (int i = 0; i < 2; ++i) {
      int c = i * 512 + tid;
      int row = c >> 3, scn = (c & 7) ^ (row & 7);
      __builtin_amdgcn_global_load_lds((const as1_uint*)(WT + (size_t)(n0 + row) * DM + kt + scn * 8),
                                       (as3_uint*)(Bd + c * 8), 16, 0, 0);
    }
  };

  // prologue: tiles 0 and 1 in flight; wait for tile 0 (6 loads still out)
  stageA(0); stageB(0);
  stageA(1); stageB(1);
  asm volatile("s_waitcnt vmcnt(6)" ::: "memory");
  __builtin_amdgcn_s_barrier();
  asm volatile("" ::: "memory");

#pragma unroll
  for (int t = 0; t < 16; ++t) {
    const unsigned short* Ab = As + (t % 3) * (256 * 64);
    const unsigned short* Bb = Bs + (t % 3) * (128 * 64);
    const bool pref = (t + 2 < 16);

    // ---- phase A: k=0 fragments + A-half of stage(t+2) + 16 MFMA ----
    bf16x8 af0[4], bf0[4];
#pragma unroll
    for (int mt = 0; mt < 4; ++mt) {
      int r = wm + mt * 16 + lw;
      af0[mt] = *(const bf16x8*)(Ab + r * 64 + ((quad ^ (r & 7)) * 8));
    }
#pragma unroll
    for (int nt = 0; nt < 4; ++nt) {
      int r = wn + nt * 16 + lw;
      bf0[nt] = *(const bf16x8*)(Bb + r * 64 + ((quad ^ (r & 7)) * 8));
    }
    if (pref) stageA(t + 2);
    __builtin_amdgcn_s_setprio(1);
#pragma unroll
    for (int mt = 0; mt < 4; ++mt)
#pragma unroll
      for (int nt = 0; nt < 4; ++nt)
        acc[mt][nt] = mfma32(af0[mt], bf0[nt], acc[mt][nt]);
    __builtin_amdgcn_s_setprio(0);

    // ---- phase B: k=1 fragments + B-half of stage(t+2) + 16 MFMA ----
    bf16x8 af1[4], bf1[4];
#pragma unroll
    for (int mt = 0; mt < 4; ++mt) {
      int r = wm + mt * 16 + lw;
      af1[mt] = *(const bf16x8*)(Ab + r * 64 + (((4 + quad) ^ (r & 7)) * 8));
    }
#pragma unroll
    for (int nt = 0; nt < 4; ++nt) {
      int r = wn + nt * 16 + lw;
      bf1[nt] = *(const bf16x8*)(Bb + r * 64 + (((4 + quad) ^ (r & 7)) * 8));
    }
    if (pref) stageB(t + 2);
    __builtin_amdgcn_s_setprio(1);
#pragma unroll
    for (int mt = 0; mt < 4; ++mt)
#pragma unroll
      for (int nt = 0; nt < 4; ++nt)
        acc[mt][nt] = mfma32(af1[mt], bf1[nt], acc[mt][nt]);
    __builtin_amdgcn_s_setprio(0);

    if (t < 15) {
      if (t < 14) asm volatile("s_waitcnt vmcnt(6)" ::: "memory");
      else        asm volatile("s_waitcnt vmcnt(0)" ::: "memory");
      __builtin_amdgcn_s_barrier();
      asm volatile("" ::: "memory");
    }
  }

  float bias4[4];
#pragma unroll
  for (int nt = 0; nt < 4; ++nt) bias4[nt] = bias[n0 + wn + nt * 16 + lw];

  if (z < 2) {
    unsigned short* dst = (z == 0) ? qo : ko;
    const float sc = (z == 0) ? Q_SCALE : 1.0f;
#pragma unroll
    for (int mt = 0; mt < 4; ++mt) {
#pragma unroll
      for (int nt = 0; nt < 4; ++nt) {
        int n = n0 + wn + nt * 16 + lw;
        int h = n >> 6, d = n & 63;
#pragma unroll
        for (int r = 0; r < 4; ++r) {
          int m = m0 + wm + mt * 16 + quad * 4 + r;
          int b = m >> 11, s = m & 2047;
          dst[((size_t)(b * NH + h) * S_LEN + s) * HD + d] = f2bf((acc[mt][nt][r] + bias4[nt]) * sc);
        }
      }
    }
  } else {
#pragma unroll
    for (int mt = 0; mt < 4; ++mt) {
#pragma unroll
      for (int nt = 0; nt < 4; ++nt) {
        int n = n0 + wn + nt * 16 + lw;
        int h = n >> 6, d = n & 63;
        int mb = m0 + wm + mt * 16 + quad * 4;
        int b = mb >> 11, s = mb & 2047;
        u16x4 pk;
#pragma unroll
        for (int r = 0; r < 4; ++r) pk[r] = f2bf(acc[mt][nt][r] + bias4[nt]);
        // 16B-unit swizzle within each 64-seq window: unit16' = unit16 ^ (d&7)
        int us = (s & ~63) | ((((s >> 3) & 7) ^ (d & 7)) << 3) | (s & 7);
        *(u16x4*)(vto + ((size_t)(b * NH + h) * HD + d) * S_LEN + us) = pk;
      }
    }
  }
}

// ---------- kernel 3: causal flash attention, all-K=32 MFMA ------------
// One 64-q-row strip per block (2048 blocks), LPT dispatch, XCD affinity.
// K+V double-buffered LDS (32 KB -> 5 blocks/CU).
// PV at full rate: K rows are PERMUTED at staging (global source row
// gsrc = (p&32)|(((p>>2)&3)<<3)|(((p>>4)&1)<<2)|(p&3)) so that per 32-kv
// sub-block, S^T MFMA #1 (LDS rows gp*32+lw) yields kv rows 8q+r and #2
// (rows gp*32+16+lw) yields 8q+4+r. Concatenating their bf16-packed outputs
// is EXACTLY the 16x16x32 A-fragment (k = quad*8+j) -- PV and accL run as
// mfma_f32_16x16x32_bf16 with zero cross-lane traffic.
// Chunk swizzle: staging ck = (idx&7)^(p&7); reads at c0 = (quad^(lw&7))*8,
// hi at c0^32 -- identical involution both sides, same for both row groups.
// Tile loop unrolled x2 with LITERAL buffer index, masked diagonal peeled,
// LDS addresses hoisted per-lane.
__global__ __launch_bounds__(256, 5) void attn(const unsigned short* __restrict__ Qb,
                                               const unsigned short* __restrict__ Kb,
                                               const unsigned short* __restrict__ Vtb,
                                               float* __restrict__ out) {
  const int flat = blockIdx.x;
  const int bh_lo = flat & 7;          // XCD affinity
  const int rest = flat >> 3;
  const int qidx = 31 - (rest >> 3);   // descending strip length (LPT)
  const int bh_hi = rest & 7;
  const int bh = bh_lo | (bh_hi << 3);
  const int b = bh >> 4, h = bh & 15;
  const int tid = threadIdx.x;
  const int wave = tid >> 6, lane = tid & 63;
  const int quad = lane >> 4, lw = lane & 15;
  const unsigned short* Qp = Qb + (size_t)bh * S_LEN * HD;
  const unsigned short* Kp = Kb + (size_t)bh * S_LEN * HD;
  const unsigned short* Vp = Vtb + (size_t)bh * HD * S_LEN;

  __shared__ __align__(16) unsigned short Kl[2][64 * 64];
  __shared__ __align__(16) unsigned short Vl[2][64 * 64];

  // Q fragments (B-operand: n=qrow=lane&15, k=quad*8+j)
  const int qbase = qidx * 64;
  bf16x8 aq[2];
#pragma unroll
  for (int kc = 0; kc < 2; ++kc)
    aq[kc] = *(const bf16x8*)(Qp + (size_t)(qbase + wave * 16 + lw) * HD + kc * 32 + quad * 8);

  u16x8 one8u;
#pragma unroll
  for (int i = 0; i < 8; ++i) one8u[i] = 0x3F80;
  const bf16x8 ones8 = __builtin_bit_cast(bf16x8, one8u);

  f32x4 accO[4];
  f32x4 accL = (f32x4){0.f, 0.f, 0.f, 0.f};
#pragma unroll
  for (int dg = 0; dg < 4; ++dg) accO[dg] = (f32x4){0.f, 0.f, 0.f, 0.f};

  const int qr = qbase + wave * 16 + lw;
  const int T = qidx + 1;

  // hoisted per-lane constants
  const int c0 = (quad ^ (lw & 7)) * 8;   // K chunk: lo features; hi = c0 ^ 32
  int w8[2];
#pragma unroll
  for (int gp = 0; gp < 2; ++gp) w8[gp] = ((gp * 4 + quad) ^ (lw & 7)) * 8;

  // staging offsets (per-lane invariant)
  int kOff[2], vOff[2], dOff[2];
#pragma unroll
  for (int i = 0; i < 2; ++i) {
    int idx = i * 256 + tid;
    int p = idx >> 3;
    int gsrc = (p & 32) | (((p >> 2) & 3) << 3) | (((p >> 4) & 1) << 2) | (p & 3);
    int ck = (idx & 7) ^ (p & 7);
    kOff[i] = gsrc * HD + ck * 8;
    vOff[i] = p * S_LEN + (idx & 7) * 8;
    dOff[i] = idx * 8;
  }

  auto stage = [&](int kvn, int buf) {
#pragma unroll
    for (int i = 0; i < 2; ++i) {
      __builtin_amdgcn_global_load_lds((const as1_uint*)(Kp + (size_t)kvn * HD + kOff[i]),
                                       (as3_uint*)(&Kl[buf][dOff[i]]), 16, 0, 0);
      __builtin_amdgcn_global_load_lds((const as1_uint*)(Vp + (size_t)kvn + vOff[i]),
                                       (as3_uint*)(&Vl[buf][dOff[i]]), 16, 0, 0);
    }
  };

  // tile body; cur/mask/pref are call-site literals
  auto body = [&](int t, int cur, bool mask, bool pref) {
    const int kv = t * 64;
    __syncthreads();  // buf[cur] staged; all waves done reading buf[cur^1]
    if (pref) stage(kv + 64, cur ^ 1);

    const unsigned short* kb = Kl[cur] + lw * 64;
    const unsigned short* vb = Vl[cur] + lw * 64;
    __builtin_amdgcn_s_setprio(1);
#pragma unroll
    for (int gp = 0; gp < 2; ++gp) {
      const unsigned short* kg = kb + gp * 2048;
      bf16x8 k00 = *(const bf16x8*)(kg + c0);                 // rows lw,    features lo
      bf16x8 k01 = *(const bf16x8*)(kg + (c0 ^ 32));          // rows lw,    features hi
      bf16x8 k10 = *(const bf16x8*)(kg + 1024 + c0);          // rows lw+16, features lo
      bf16x8 k11 = *(const bf16x8*)(kg + 1024 + (c0 ^ 32));   // rows lw+16, features hi

      f32x4 s0 = (f32x4){0.f, 0.f, 0.f, 0.f};
      f32x4 s1 = (f32x4){0.f, 0.f, 0.f, 0.f};
      s0 = mfma32(k00, aq[0], s0);
      s0 = mfma32(k01, aq[1], s0);
      s1 = mfma32(k10, aq[0], s1);
      s1 = mfma32(k11, aq[1], s1);

      if (mask) {
        const int kvb = kv + gp * 32 + 8 * quad;
#pragma unroll
        for (int r = 0; r < 4; ++r) {
          float e0 = __builtin_amdgcn_exp2f(s0[r]);
          float e1 = __builtin_amdgcn_exp2f(s1[r]);
          s0[r] = (kvb + r > qr) ? 0.f : e0;
          s1[r] = (kvb + 4 + r > qr) ? 0.f : e1;
        }
      } else {
#pragma unroll
        for (int r = 0; r < 4; ++r) {
          s0[r] = __builtin_amdgcn_exp2f(s0[r]);
          s1[r] = __builtin_amdgcn_exp2f(s1[r]);
        }
      }
      // pack to x32 A-fragment: slots j=0..3 <- s0 (kv 8q+r), j=4..7 <- s1 (kv 8q+4+r)
      u32x4 pw;
      pw[0] = (fbits(s0[1]) & 0xFFFF0000u) | (fbits(s0[0]) >> 16);
      pw[1] = (fbits(s0[3]) & 0xFFFF0000u) | (fbits(s0[2]) >> 16);
      pw[2] = (fbits(s1[1]) & 0xFFFF0000u) | (fbits(s1[0]) >> 16);
      pw[3] = (fbits(s1[3]) & 0xFFFF0000u) | (fbits(s1[2]) >> 16);
      bf16x8 af = __builtin_bit_cast(bf16x8, pw);

#pragma unroll
      for (int dg = 0; dg < 4; ++dg) {
        bf16x8 vf = *(const bf16x8*)(vb + dg * 1024 + w8[gp]);
        accO[dg] = mfma32(af, vf, accO[dg]);
      }
      accL = mfma32(af, ones8, accL);
    }
    __builtin_amdgcn_s_setprio(0);
  };

  // prologue: stage tile 0 into buffer 0
  stage(0, 0);

  int t = 0;
  const int nmain = T - 1;  // tiles without causal mask
  for (; t + 1 < nmain; t += 2) {
    body(t, 0, false, true);
    body(t + 1, 1, false, true);
  }
  if (t < nmain) { body(t, 0, false, true); ++t; }
  if (t & 1) body(t, 1, true, false);
  else       body(t, 0, true, false);

  float* op = out + ((size_t)b * S_LEN + qbase + wave * 16 + quad * 4) * DM + h * HD + lw;
#pragma unroll
  for (int r = 0; r < 4; ++r) {
    float inv = 1.0f / accL[r];
#pragma unroll
    for (int dg = 0; dg < 4; ++dg) op[(size_t)r * DM + dg * 16] = accO[dg][r] * inv;
  }
}

extern "C" void kernel_launch(void* const* d_in, const int* in_sizes, int n_in,
                              void* d_out, int out_size, void* d_ws, size_t ws_size,
                              hipStream_t stream) {
  const float* x = (const float*)d_in[0];
  const float* Wq = (const float*)d_in[1];
  const float* bq = (const float*)d_in[2];
  const float* Wk = (const float*)d_in[3];
  const float* bk = (const float*)d_in[4];
  const float* Wv = (const float*)d_in[5];
  const float* bv = (const float*)d_in[6];
  float* out = (float*)d_out;

  char* ws = (char*)d_ws;
  unsigned short* xb = (unsigned short*)(ws + 0);          // 16 MB: X bf16 (8192,1024)
  unsigned short* wt = (unsigned short*)(ws + 16777216);   // 6 MB: Wq/Wk/Wv^T bf16
  unsigned short* qb = (unsigned short*)(ws + 23068672);   // 16 MB: Q*scale (B,H,S,64)
  unsigned short* kb = (unsigned short*)(ws + 39845888);   // 16 MB: K (B,H,S,64)
  unsigned short* vt = (unsigned short*)(ws + 56623104);   // 16 MB: V^T swizzled (B,H,64,S)

  static bool qkv_attr_once = []() {
    hipFuncSetAttribute((const void*)qkv_gemm,
                        hipFuncAttributeMaxDynamicSharedMemorySize, QKV_LDS_BYTES);
    return true;
  }();
  (void)qkv_attr_once;

  hipLaunchKernelGGL(cvt_all, dim3(7168), dim3(256), 0, stream, x, xb, Wq, Wk, Wv, wt);
  hipLaunchKernelGGL(qkv_gemm, dim3(32, 8, 3), dim3(512), QKV_LDS_BYTES, stream,
                     xb, wt, bq, bk, bv, qb, kb, vt);
  hipLaunchKernelGGL(attn, dim3(2048), dim3(256), 0, stream, qb, kb, vt, out);
}